// Round 2
// baseline (1941.720 us; speedup 1.0000x reference)
//
#include <hip/hip_runtime.h>
#include <hip/hip_bf16.h>

// HiLo attention forward, fp32 baseline. All tensors NHWC (channels-last).
// x: [8,4096,512] == [B,H=64,W=64,C=512] NHWC already.
// out: [8,4096,512], cols 0-255 = low path, 256-511 = high path.

constexpr int BATCH = 8;

// ---------------------------------------------------------------------------
// pool: low = avgpool2x2(x), high = upsample(low) - x       (NHWC, C=512)
// grid: B*32*32*128 threads (one float4 of channels per thread)
// ---------------------------------------------------------------------------
__global__ __launch_bounds__(256) void pool_kernel(const float* __restrict__ x,
                                                   float* __restrict__ low,
                                                   float* __restrict__ high) {
    int idx = blockIdx.x * 256 + threadIdx.x;
    int c4 = idx & 127;          // 512/4 channel-quads
    int p  = idx >> 7;
    int px = p & 31, py = (p >> 5) & 31, b = p >> 10;
    size_t base = ((size_t)(b * 64 + 2 * py) * 64 + 2 * px) * 512 + c4 * 4;
    float4 v00 = *(const float4*)(x + base);
    float4 v01 = *(const float4*)(x + base + 512);
    float4 v10 = *(const float4*)(x + base + 64 * 512);
    float4 v11 = *(const float4*)(x + base + 64 * 512 + 512);
    float4 a;
    a.x = 0.25f * (v00.x + v01.x + v10.x + v11.x);
    a.y = 0.25f * (v00.y + v01.y + v10.y + v11.y);
    a.z = 0.25f * (v00.z + v01.z + v10.z + v11.z);
    a.w = 0.25f * (v00.w + v01.w + v10.w + v11.w);
    *(float4*)(low + ((size_t)(b * 32 + py) * 32 + px) * 512 + c4 * 4) = a;
    float4 h;
    h.x = a.x - v00.x; h.y = a.y - v00.y; h.z = a.z - v00.z; h.w = a.w - v00.w;
    *(float4*)(high + base) = h;
    h.x = a.x - v01.x; h.y = a.y - v01.y; h.z = a.z - v01.z; h.w = a.w - v01.w;
    *(float4*)(high + base + 512) = h;
    h.x = a.x - v10.x; h.y = a.y - v10.y; h.z = a.z - v10.z; h.w = a.w - v10.w;
    *(float4*)(high + base + 64 * 512) = h;
    h.x = a.x - v11.x; h.y = a.y - v11.y; h.z = a.z - v11.z; h.w = a.w - v11.w;
    *(float4*)(high + base + 64 * 512 + 512) = h;
}

// ---------------------------------------------------------------------------
// depthwise 3x3 + bias, NHWC, SAME zero-padding. w: [C,9] flat, bias: [C].
// one float4 of channels per thread.
// ---------------------------------------------------------------------------
__global__ __launch_bounds__(256) void dw3x3_kernel(const float* __restrict__ in,
                                                    const float* __restrict__ w,
                                                    const float* __restrict__ bias,
                                                    float* __restrict__ out,
                                                    int Bn, int Hn, int Wn, int Cn) {
    int C4 = Cn >> 2;
    int idx = blockIdx.x * 256 + threadIdx.x;
    if (idx >= Bn * Hn * Wn * C4) return;
    int c4  = idx % C4;
    int pix = idx / C4;
    int x0 = pix % Wn;
    int y0 = (pix / Wn) % Hn;
    int b  = pix / (Wn * Hn);
    int c  = c4 << 2;

    // 36 contiguous weights (4 channels x 9 taps), aligned: c%4==0 -> 144B multiple
    float wf[36];
    const float4* wp = (const float4*)(w + (size_t)c * 9);
#pragma unroll
    for (int t = 0; t < 9; ++t) {
        float4 tv = wp[t];
        wf[4 * t] = tv.x; wf[4 * t + 1] = tv.y; wf[4 * t + 2] = tv.z; wf[4 * t + 3] = tv.w;
    }
    float4 acc = *(const float4*)(bias + c);
#pragma unroll
    for (int ky = 0; ky < 3; ++ky) {
        int yy = y0 + ky - 1;
        if (yy < 0 || yy >= Hn) continue;
#pragma unroll
        for (int kx = 0; kx < 3; ++kx) {
            int xx = x0 + kx - 1;
            if (xx < 0 || xx >= Wn) continue;
            float4 v = *(const float4*)(in + ((size_t)(b * Hn + yy) * Wn + xx) * Cn + c);
            int wi = ky * 3 + kx;
            acc.x += v.x * wf[0 * 9 + wi];
            acc.y += v.y * wf[1 * 9 + wi];
            acc.z += v.z * wf[2 * 9 + wi];
            acc.w += v.w * wf[3 * 9 + wi];
        }
    }
    *(float4*)(out + ((size_t)(b * Hn + y0) * Wn + x0) * Cn + c) = acc;
}

// ---------------------------------------------------------------------------
// pointwise 1x1 conv as GEMM + bias.
// A: [M,K] activations row-major, Wt: [N,K] weights row-major ([co][ci]).
// out[m, ocol + n] at row stride ostride.
// BM=BN=128, BK=16, 256 threads, 8x8 micro-tile.
// ---------------------------------------------------------------------------
__global__ __launch_bounds__(256) void pw_gemm_kernel(const float* __restrict__ A,
                                                      const float* __restrict__ Wt,
                                                      const float* __restrict__ bias,
                                                      float* __restrict__ out,
                                                      int M, int N, int K,
                                                      int ostride, int ocol) {
    __shared__ float As[16][132];
    __shared__ float Bs[16][132];
    int tid = threadIdx.x;
    int bm = blockIdx.y * 128, bn = blockIdx.x * 128;
    int tx = tid & 15, ty = tid >> 4;

    float c[8][8];
#pragma unroll
    for (int i = 0; i < 8; ++i)
#pragma unroll
        for (int j = 0; j < 8; ++j) c[i][j] = 0.f;

    int lrow = tid >> 1;           // 0..127
    int lk   = (tid & 1) * 8;      // 0 or 8
    const float* Ap = A  + (size_t)(bm + lrow) * K + lk;
    const float* Bp = Wt + (size_t)(bn + lrow) * K + lk;

    for (int k0 = 0; k0 < K; k0 += 16) {
        float4 a0 = *(const float4*)(Ap + k0);
        float4 a1 = *(const float4*)(Ap + k0 + 4);
        float4 b0 = *(const float4*)(Bp + k0);
        float4 b1 = *(const float4*)(Bp + k0 + 4);
        __syncthreads();   // previous iteration's LDS reads done
        As[lk + 0][lrow] = a0.x; As[lk + 1][lrow] = a0.y;
        As[lk + 2][lrow] = a0.z; As[lk + 3][lrow] = a0.w;
        As[lk + 4][lrow] = a1.x; As[lk + 5][lrow] = a1.y;
        As[lk + 6][lrow] = a1.z; As[lk + 7][lrow] = a1.w;
        Bs[lk + 0][lrow] = b0.x; Bs[lk + 1][lrow] = b0.y;
        Bs[lk + 2][lrow] = b0.z; Bs[lk + 3][lrow] = b0.w;
        Bs[lk + 4][lrow] = b1.x; Bs[lk + 5][lrow] = b1.y;
        Bs[lk + 6][lrow] = b1.z; Bs[lk + 7][lrow] = b1.w;
        __syncthreads();
#pragma unroll
        for (int k = 0; k < 16; ++k) {
            float4 av0 = *(const float4*)&As[k][ty * 8];
            float4 av1 = *(const float4*)&As[k][ty * 8 + 4];
            float4 bv0 = *(const float4*)&Bs[k][tx * 8];
            float4 bv1 = *(const float4*)&Bs[k][tx * 8 + 4];
            float a_[8] = {av0.x, av0.y, av0.z, av0.w, av1.x, av1.y, av1.z, av1.w};
            float b_[8] = {bv0.x, bv0.y, bv0.z, bv0.w, bv1.x, bv1.y, bv1.z, bv1.w};
#pragma unroll
            for (int i = 0; i < 8; ++i)
#pragma unroll
                for (int j = 0; j < 8; ++j) c[i][j] += a_[i] * b_[j];
        }
    }
#pragma unroll
    for (int i = 0; i < 8; ++i) {
        int row = bm + ty * 8 + i;
        float* op = out + (size_t)row * ostride + ocol + bn + tx * 8;
        float4 r0, r1;
        r0.x = c[i][0] + bias[bn + tx * 8 + 0];
        r0.y = c[i][1] + bias[bn + tx * 8 + 1];
        r0.z = c[i][2] + bias[bn + tx * 8 + 2];
        r0.w = c[i][3] + bias[bn + tx * 8 + 3];
        r1.x = c[i][4] + bias[bn + tx * 8 + 4];
        r1.y = c[i][5] + bias[bn + tx * 8 + 5];
        r1.z = c[i][6] + bias[bn + tx * 8 + 6];
        r1.w = c[i][7] + bias[bn + tx * 8 + 7];
        *(float4*)op = r0;
        *(float4*)(op + 4) = r1;
    }
}

// ---------------------------------------------------------------------------
// low-frequency attention, flash-style, fp32.
// lq:  [B,4096,256]  channel = head*64+d
// lkv: [B,1024,512]  channel = kv*256 + head*64 + d
// lx:  [B,4096,256]  channel = head*64+d
// one query per thread, 256 queries/block; K/V tiled 64 keys in LDS.
// grid: B*4*16 = 512 blocks.
// ---------------------------------------------------------------------------
__global__ __launch_bounds__(256) void low_attn_kernel(const float* __restrict__ lq,
                                                       const float* __restrict__ lkv,
                                                       float* __restrict__ lx) {
    __shared__ float Ks[64][64];
    __shared__ float Vs[64][64];
    int bx = blockIdx.x;
    int qc = bx & 15;
    int h  = (bx >> 4) & 3;
    int b  = bx >> 6;
    int tid = threadIdx.x;
    int q = qc * 256 + tid;

    float4 qr[16];
    const float* qp = lq + ((size_t)b * 4096 + q) * 256 + h * 64;
#pragma unroll
    for (int i = 0; i < 16; ++i) qr[i] = *(const float4*)(qp + i * 4);

    float4 acc[16];
#pragma unroll
    for (int i = 0; i < 16; ++i) { acc[i].x = 0.f; acc[i].y = 0.f; acc[i].z = 0.f; acc[i].w = 0.f; }
    float m = -1e30f, l = 0.f;

    const float* kvbase = lkv + (size_t)b * 1024 * 512 + h * 64;

    for (int k0 = 0; k0 < 1024; k0 += 64) {
        __syncthreads();
#pragma unroll
        for (int j = 0; j < 4; ++j) {
            int f = tid + j * 256;       // 1024 float4s: key = f/16, dquad = f%16
            int key = f >> 4;
            int dq  = f & 15;
            const float* src = kvbase + (size_t)(k0 + key) * 512 + dq * 4;
            *(float4*)&Ks[key][dq * 4] = *(const float4*)(src);
            *(float4*)&Vs[key][dq * 4] = *(const float4*)(src + 256);
        }
        __syncthreads();
        for (int k = 0; k < 64; ++k) {
            float s = 0.f;
#pragma unroll
            for (int i = 0; i < 16; ++i) {
                float4 kv = *(const float4*)&Ks[k][i * 4];
                s += qr[i].x * kv.x + qr[i].y * kv.y + qr[i].z * kv.z + qr[i].w * kv.w;
            }
            s *= 0.125f;
            float p;
            if (s <= m) {
                p = __expf(s - m);
            } else {
                float corr = __expf(m - s);
                l *= corr;
#pragma unroll
                for (int i = 0; i < 16; ++i) {
                    acc[i].x *= corr; acc[i].y *= corr; acc[i].z *= corr; acc[i].w *= corr;
                }
                m = s;
                p = 1.f;
            }
            l += p;
#pragma unroll
            for (int i = 0; i < 16; ++i) {
                float4 vv = *(const float4*)&Vs[k][i * 4];
                acc[i].x += p * vv.x; acc[i].y += p * vv.y;
                acc[i].z += p * vv.z; acc[i].w += p * vv.w;
            }
        }
    }
    float inv = 1.f / l;
    float* op = lx + ((size_t)b * 4096 + q) * 256 + h * 64;
#pragma unroll
    for (int i = 0; i < 16; ++i) {
        float4 r;
        r.x = acc[i].x * inv; r.y = acc[i].y * inv;
        r.z = acc[i].z * inv; r.w = acc[i].w * inv;
        *(float4*)(op + i * 4) = r;
    }
}

// ---------------------------------------------------------------------------
// high-frequency windowed attention (2x2 windows), fp32.
// hqkv: [B,64,64,768] channel = qkv*256 + head*64 + d
// hx:   [B,64,64,256] channel = head*64 + d
// one thread per (b, window, head). grid: 8*1024*4/256 = 128 blocks.
// ---------------------------------------------------------------------------
__global__ __launch_bounds__(256) void high_attn_kernel(const float* __restrict__ hqkv,
                                                        float* __restrict__ hx) {
    int idx = blockIdx.x * 256 + threadIdx.x;
    int h = idx & 3;
    int g = (idx >> 2) & 1023;
    int b = idx >> 12;
    int gy = g >> 5, gx = g & 31;
    size_t pbase[4];
    size_t obase[4];
#pragma unroll
    for (int t = 0; t < 4; ++t) {
        int y = gy * 2 + (t >> 1);
        int x = gx * 2 + (t & 1);
        size_t pix = (size_t)(b * 64 + y) * 64 + x;
        pbase[t] = pix * 768;
        obase[t] = pix * 256;
    }
    int co = h * 64;

    float s[4][4];
#pragma unroll
    for (int i = 0; i < 4; ++i)
#pragma unroll
        for (int j = 0; j < 4; ++j) s[i][j] = 0.f;

    for (int dq = 0; dq < 16; ++dq) {
        float4 qv[4], kv[4];
#pragma unroll
        for (int t = 0; t < 4; ++t) {
            qv[t] = *(const float4*)(hqkv + pbase[t] + co + dq * 4);
            kv[t] = *(const float4*)(hqkv + pbase[t] + 256 + co + dq * 4);
        }
#pragma unroll
        for (int i = 0; i < 4; ++i)
#pragma unroll
            for (int j = 0; j < 4; ++j)
                s[i][j] += qv[i].x * kv[j].x + qv[i].y * kv[j].y +
                           qv[i].z * kv[j].z + qv[i].w * kv[j].w;
    }

    float p[4][4];
#pragma unroll
    for (int i = 0; i < 4; ++i) {
        float mx = -1e30f;
#pragma unroll
        for (int j = 0; j < 4; ++j) { s[i][j] *= 0.125f; mx = fmaxf(mx, s[i][j]); }
        float sum = 0.f;
#pragma unroll
        for (int j = 0; j < 4; ++j) { p[i][j] = __expf(s[i][j] - mx); sum += p[i][j]; }
        float inv = 1.f / sum;
#pragma unroll
        for (int j = 0; j < 4; ++j) p[i][j] *= inv;
    }

    for (int dq = 0; dq < 16; ++dq) {
        float4 vv[4];
#pragma unroll
        for (int t = 0; t < 4; ++t)
            vv[t] = *(const float4*)(hqkv + pbase[t] + 512 + co + dq * 4);
#pragma unroll
        for (int i = 0; i < 4; ++i) {
            float4 o;
            o.x = p[i][0] * vv[0].x + p[i][1] * vv[1].x + p[i][2] * vv[2].x + p[i][3] * vv[3].x;
            o.y = p[i][0] * vv[0].y + p[i][1] * vv[1].y + p[i][2] * vv[2].y + p[i][3] * vv[3].y;
            o.z = p[i][0] * vv[0].z + p[i][1] * vv[1].z + p[i][2] * vv[2].z + p[i][3] * vv[3].z;
            o.w = p[i][0] * vv[0].w + p[i][1] * vv[1].w + p[i][2] * vv[2].w + p[i][3] * vv[3].w;
            *(float4*)(hx + obase[i] + co + dq * 4) = o;
        }
    }
}

// ---------------------------------------------------------------------------
extern "C" void kernel_launch(void* const* d_in, const int* in_sizes, int n_in,
                              void* d_out, int out_size, void* d_ws, size_t ws_size,
                              hipStream_t stream) {
    const float* x        = (const float*)d_in[0];
    const float* lq_dw    = (const float*)d_in[1];
    const float* lq_dwb   = (const float*)d_in[2];
    const float* lq_pw    = (const float*)d_in[3];
    const float* lq_pwb   = (const float*)d_in[4];
    const float* lkv_dw   = (const float*)d_in[5];
    const float* lkv_dwb  = (const float*)d_in[6];
    const float* lkv_pw   = (const float*)d_in[7];
    const float* lkv_pwb  = (const float*)d_in[8];
    const float* lproj_dw = (const float*)d_in[9];
    const float* lproj_dwb= (const float*)d_in[10];
    const float* lproj_pw = (const float*)d_in[11];
    const float* lproj_pwb= (const float*)d_in[12];
    const float* hqkv_dw  = (const float*)d_in[13];
    const float* hqkv_dwb = (const float*)d_in[14];
    const float* hqkv_pw  = (const float*)d_in[15];
    const float* hqkv_pwb = (const float*)d_in[16];
    const float* hproj_dw = (const float*)d_in[17];
    const float* hproj_dwb= (const float*)d_in[18];
    const float* hproj_pw = (const float*)d_in[19];
    const float* hproj_pwb= (const float*)d_in[20];
    float* out = (float*)d_out;

    float* ws = (float*)d_ws;
    // workspace layout (floats), lifetimes arranged for reuse; peak 224 MB
    float* tdw   = ws;                       // 16,777,216  [B,4096,512] scratch
    float* high  = ws + 16777216;            // 16,777,216  [B,64,64,512]
    float* low   = ws + 33554432;            //  4,194,304  [B,32,32,512]
    float* l_q   = ws + 37748736;            //  8,388,608  [B,4096,256]
    float* l_kv  = ws + 46137344;            //  4,194,304  [B,1024,512]
    float* l_x   = ws + 50331648;            //  8,388,608  [B,4096,256]
    float* h_qkv = ws + 33554432;            // 25,165,824  [B,4096,768] (reuses low..l_x)
    float* h_x   = high;                     //  8,388,608  [B,64,64,256] (reuses high)

    // 1. pool: low + high
    pool_kernel<<<4096, 256, 0, stream>>>(x, low, high);

    // 2. l_q = dsc(x)
    dw3x3_kernel<<<16384, 256, 0, stream>>>(x, lq_dw, lq_dwb, tdw, BATCH, 64, 64, 512);
    pw_gemm_kernel<<<dim3(2, 256), 256, 0, stream>>>(tdw, lq_pw, lq_pwb, l_q,
                                                     32768, 256, 512, 256, 0);
    // 3. l_kv = dsc(low)
    dw3x3_kernel<<<4096, 256, 0, stream>>>(low, lkv_dw, lkv_dwb, tdw, BATCH, 32, 32, 512);
    pw_gemm_kernel<<<dim3(4, 64), 256, 0, stream>>>(tdw, lkv_pw, lkv_pwb, l_kv,
                                                    8192, 512, 512, 512, 0);
    // 4. low attention
    low_attn_kernel<<<512, 256, 0, stream>>>(l_q, l_kv, l_x);

    // 5. l_out = dsc(l_x) -> out cols 0..255
    dw3x3_kernel<<<8192, 256, 0, stream>>>(l_x, lproj_dw, lproj_dwb, tdw, BATCH, 64, 64, 256);
    pw_gemm_kernel<<<dim3(2, 256), 256, 0, stream>>>(tdw, lproj_pw, lproj_pwb, out,
                                                     32768, 256, 256, 512, 0);
    // 6. h_qkv = dsc(high)
    dw3x3_kernel<<<16384, 256, 0, stream>>>(high, hqkv_dw, hqkv_dwb, tdw, BATCH, 64, 64, 512);
    pw_gemm_kernel<<<dim3(6, 256), 256, 0, stream>>>(tdw, hqkv_pw, hqkv_pwb, h_qkv,
                                                     32768, 768, 512, 768, 0);
    // 7. high (windowed) attention
    high_attn_kernel<<<128, 256, 0, stream>>>(h_qkv, h_x);

    // 8. h_out = dsc(h_x) -> out cols 256..511
    dw3x3_kernel<<<8192, 256, 0, stream>>>(h_x, hproj_dw, hproj_dwb, tdw, BATCH, 64, 64, 256);
    pw_gemm_kernel<<<dim3(2, 256), 256, 0, stream>>>(tdw, hproj_pw, hproj_pwb, out,
                                                     32768, 256, 256, 512, 256);
}

// Round 6
// 870.107 us; speedup vs baseline: 2.2316x; 2.2316x over previous
//
#include <hip/hip_runtime.h>
#include <hip/hip_bf16.h>

// HiLo attention forward. NHWC everywhere. Round 5:
//  - low attention: bf16 MFMA flash (swapped QK^T, wave-private swizzled P LDS)
//  - ALL pointwise convs: bf16 MFMA GEMM, no LDS/no barriers (L2-resident panels)
//  - dw3x3 emits bf16 directly; weights pre-cast to bf16 once per launch

constexpr int BATCH = 8;

typedef __attribute__((ext_vector_type(8))) short  bf16x8;   // 8 bf16 (4 VGPR)
typedef __attribute__((ext_vector_type(4))) float  f32x4;
typedef __attribute__((ext_vector_type(4))) ushort ushortx4;

__device__ __forceinline__ ushort bfround(float x) {   // fp32 -> bf16 RNE
    unsigned u = __float_as_uint(x);
    u += 0x7fff + ((u >> 16) & 1);
    return (ushort)(u >> 16);
}

// ---------------------------------------------------------------------------
// weight cast: 5 fp32 [N,K] weight mats -> concatenated bf16 buffer
// segments: lq@0(131072) lkv@131072(262144) lproj@393216(65536)
//           hqkv@458752(393216) hproj@851968(65536)  total 917504
// ---------------------------------------------------------------------------
__global__ __launch_bounds__(256) void wconv_kernel(const float* __restrict__ s0,
                                                    const float* __restrict__ s1,
                                                    const float* __restrict__ s2,
                                                    const float* __restrict__ s3,
                                                    const float* __restrict__ s4,
                                                    ushort* __restrict__ dst) {
    int i = blockIdx.x * 256 + threadIdx.x;
    const float* s; int off;
    if      (i < 131072) { s = s0; off = 0; }
    else if (i < 393216) { s = s1; off = 131072; }
    else if (i < 458752) { s = s2; off = 393216; }
    else if (i < 851968) { s = s3; off = 458752; }
    else                 { s = s4; off = 851968; }
    dst[i] = bfround(s[i - off]);
}

// ---------------------------------------------------------------------------
// pool: low = avgpool2x2(x), high = upsample(low) - x       (NHWC, C=512)
// ---------------------------------------------------------------------------
__global__ __launch_bounds__(256) void pool_kernel(const float* __restrict__ x,
                                                   float* __restrict__ low,
                                                   float* __restrict__ high) {
    int idx = blockIdx.x * 256 + threadIdx.x;
    int c4 = idx & 127;
    int p  = idx >> 7;
    int px = p & 31, py = (p >> 5) & 31, b = p >> 10;
    size_t base = ((size_t)(b * 64 + 2 * py) * 64 + 2 * px) * 512 + c4 * 4;
    float4 v00 = *(const float4*)(x + base);
    float4 v01 = *(const float4*)(x + base + 512);
    float4 v10 = *(const float4*)(x + base + 64 * 512);
    float4 v11 = *(const float4*)(x + base + 64 * 512 + 512);
    float4 a;
    a.x = 0.25f * (v00.x + v01.x + v10.x + v11.x);
    a.y = 0.25f * (v00.y + v01.y + v10.y + v11.y);
    a.z = 0.25f * (v00.z + v01.z + v10.z + v11.z);
    a.w = 0.25f * (v00.w + v01.w + v10.w + v11.w);
    *(float4*)(low + ((size_t)(b * 32 + py) * 32 + px) * 512 + c4 * 4) = a;
    float4 h;
    h.x = a.x - v00.x; h.y = a.y - v00.y; h.z = a.z - v00.z; h.w = a.w - v00.w;
    *(float4*)(high + base) = h;
    h.x = a.x - v01.x; h.y = a.y - v01.y; h.z = a.z - v01.z; h.w = a.w - v01.w;
    *(float4*)(high + base + 512) = h;
    h.x = a.x - v10.x; h.y = a.y - v10.y; h.z = a.z - v10.z; h.w = a.w - v10.w;
    *(float4*)(high + base + 64 * 512) = h;
    h.x = a.x - v11.x; h.y = a.y - v11.y; h.z = a.z - v11.z; h.w = a.w - v11.w;
    *(float4*)(high + base + 64 * 512 + 512) = h;
}

// ---------------------------------------------------------------------------
// depthwise 3x3 + bias, NHWC, SAME zero-pad, fp32 in -> bf16 out.
// ---------------------------------------------------------------------------
__global__ __launch_bounds__(256) void dw3x3_bf16_kernel(const float* __restrict__ in,
                                                         const float* __restrict__ w,
                                                         const float* __restrict__ bias,
                                                         ushort* __restrict__ out,
                                                         int Bn, int Hn, int Wn, int Cn) {
    int C4 = Cn >> 2;
    int idx = blockIdx.x * 256 + threadIdx.x;
    if (idx >= Bn * Hn * Wn * C4) return;
    int c4  = idx % C4;
    int pix = idx / C4;
    int x0 = pix % Wn;
    int y0 = (pix / Wn) % Hn;
    int b  = pix / (Wn * Hn);
    int c  = c4 << 2;

    float wf[36];
    const float4* wp = (const float4*)(w + (size_t)c * 9);
#pragma unroll
    for (int t = 0; t < 9; ++t) {
        float4 tv = wp[t];
        wf[4 * t] = tv.x; wf[4 * t + 1] = tv.y; wf[4 * t + 2] = tv.z; wf[4 * t + 3] = tv.w;
    }
    float4 acc = *(const float4*)(bias + c);
#pragma unroll
    for (int ky = 0; ky < 3; ++ky) {
        int yy = y0 + ky - 1;
        if (yy < 0 || yy >= Hn) continue;
#pragma unroll
        for (int kx = 0; kx < 3; ++kx) {
            int xx = x0 + kx - 1;
            if (xx < 0 || xx >= Wn) continue;
            float4 v = *(const float4*)(in + ((size_t)(b * Hn + yy) * Wn + xx) * Cn + c);
            int wi = ky * 3 + kx;
            acc.x += v.x * wf[0 * 9 + wi];
            acc.y += v.y * wf[1 * 9 + wi];
            acc.z += v.z * wf[2 * 9 + wi];
            acc.w += v.w * wf[3 * 9 + wi];
        }
    }
    ushortx4 r;
    r.x = bfround(acc.x); r.y = bfround(acc.y);
    r.z = bfround(acc.z); r.w = bfround(acc.w);
    *(ushortx4*)(out + ((size_t)(b * Hn + y0) * Wn + x0) * Cn + c) = r;
}

// ---------------------------------------------------------------------------
// bf16 MFMA GEMM + bias. A: [M,K] bf16 row-major, W: [N,K] bf16 row-major.
// No LDS, no barriers: per-block A-panel (128xK) and W-panel are L1/L2-hot;
// fragments load straight from global (same structure as low_attn_mfma).
// 256 thr = 4 waves (2x2), wave owns 64x64; acc 4x4 of 16x16.
// grid: (N/128, M/128). BF16OUT: out=ushort* (stride ostride), else float*
// at column offset ocol.
// ---------------------------------------------------------------------------
template<int K, bool BF16OUT>
__global__ __launch_bounds__(256) void mfma_gemm(const ushort* __restrict__ A,
                                                 const ushort* __restrict__ W,
                                                 const float* __restrict__ bias,
                                                 void* __restrict__ outv,
                                                 int ostride, int ocol) {
    int tid = threadIdx.x;
    int w = tid >> 6, l = tid & 63, c = l & 15, g = l >> 4;
    int wr = w >> 1, wc = w & 1;
    int bm = blockIdx.y * 128, bn = blockIdx.x * 128;

    const ushort* Ab = A + (size_t)(bm + wr * 64 + c) * K + g * 8;
    const ushort* Wb = W + (size_t)(bn + wc * 64 + c) * K + g * 8;

    f32x4 acc[4][4];
#pragma unroll
    for (int mt = 0; mt < 4; ++mt)
#pragma unroll
        for (int nt = 0; nt < 4; ++nt) acc[mt][nt] = (f32x4)(0.f);

#pragma unroll
    for (int kt = 0; kt < K / 32; ++kt) {
        bf16x8 af[4], bf_[4];
#pragma unroll
        for (int mt = 0; mt < 4; ++mt)
            af[mt] = *(const bf16x8*)(Ab + (size_t)mt * 16 * K + kt * 32);
#pragma unroll
        for (int nt = 0; nt < 4; ++nt)
            bf_[nt] = *(const bf16x8*)(Wb + (size_t)nt * 16 * K + kt * 32);
#pragma unroll
        for (int mt = 0; mt < 4; ++mt)
#pragma unroll
            for (int nt = 0; nt < 4; ++nt)
                acc[mt][nt] = __builtin_amdgcn_mfma_f32_16x16x32_bf16(
                    af[mt], bf_[nt], acc[mt][nt], 0, 0, 0);
    }

    // C/D: row(M) = 4g + reg, col(N) = c
#pragma unroll
    for (int mt = 0; mt < 4; ++mt) {
        int m = bm + wr * 64 + mt * 16 + 4 * g;
#pragma unroll
        for (int nt = 0; nt < 4; ++nt) {
            int n = bn + wc * 64 + nt * 16 + c;
            float bs = bias[n];
#pragma unroll
            for (int r = 0; r < 4; ++r) {
                float v = acc[mt][nt][r] + bs;
                if (BF16OUT)
                    ((ushort*)outv)[(size_t)(m + r) * ostride + n] = bfround(v);
                else
                    ((float*)outv)[(size_t)(m + r) * ostride + ocol + n] = v;
            }
        }
    }
}

// ---------------------------------------------------------------------------
// vtrans: V^T from l_kv(bf16). in: [B,1024,512] ch=256+h*64+d (bf16)
// out vt: [b*4+h][64][1024] bf16. thread per (b,h,k).
// ---------------------------------------------------------------------------
__global__ __launch_bounds__(256) void vtrans_kernel(const ushort* __restrict__ lkvb,
                                                     ushort* __restrict__ vt) {
    int gid = blockIdx.x * 256 + threadIdx.x;   // 32768
    int k  = gid & 1023;
    int bh = gid >> 10;                         // b*4+h
    const ushort* src = lkvb + ((size_t)(bh >> 2) * 1024 + k) * 512 + 256 + (bh & 3) * 64;
    ushort v[64];
#pragma unroll
    for (int i = 0; i < 8; ++i) {
        bf16x8 t = *(const bf16x8*)(src + i * 8);
#pragma unroll
        for (int e = 0; e < 8; ++e) v[i * 8 + e] = (ushort)t[e];
    }
    ushort* dst = vt + (size_t)bh * 64 * 1024 + k;
#pragma unroll
    for (int d = 0; d < 64; ++d) dst[(size_t)d * 1024] = v[d];
}

// ---------------------------------------------------------------------------
// low-frequency MFMA flash attention.
// lqb: [B,4096,256] bf16 (ch=h*64+d); lkvb: [B,1024,512] bf16 (K at ch=h*64+d)
// vt:  [b*4+h][64][1024] bf16 (V^T); lx: [B,4096,256] fp32
// grid 2048 = b(3b)|h(2b)|qblock(6b); 256 thr = 4 waves; 16 queries/wave.
// Swapped QK^T: S^T = K*Q^T so each lane owns ONE query's stats.
// P staged in wave-private XOR-swizzled LDS to form PV A-fragments.
// ---------------------------------------------------------------------------
__global__ __launch_bounds__(256) void low_attn_mfma(const ushort* __restrict__ lqb,
                                                     const ushort* __restrict__ lkvb,
                                                     const ushort* __restrict__ vt,
                                                     float* __restrict__ lx) {
    __shared__ ushort Ps[4][1024];      // per-wave [16q][64k] bf16, swizzled

    const float KSC = 0.18033688011112042f;   // SCALE * log2(e)

    int tid = threadIdx.x;
    int w = tid >> 6, l = tid & 63;
    int c = l & 15, g = l >> 4;
    int bx = blockIdx.x;
    int qb = bx & 63, h = (bx >> 6) & 3, b = bx >> 8;
    int qbase = qb * 64 + w * 16;

    // Q fragments (B-operand of S^T): lane holds Q[q=c][d = ks*32 + 8g + e]
    const ushort* qp = lqb + ((size_t)b * 4096 + qbase + c) * 256 + h * 64 + g * 8;
    bf16x8 qf0 = *(const bf16x8*)(qp);
    bf16x8 qf1 = *(const bf16x8*)(qp + 32);

    const ushort* kbase = lkvb + (size_t)b * 1024 * 512 + h * 64 + g * 8;
    const ushort* vbase = vt + (size_t)(b * 4 + h) * 64 * 1024 + g * 8;

    float m = -1e30f, lsum = 0.f;
    f32x4 o[4];
#pragma unroll
    for (int dt = 0; dt < 4; ++dt) o[dt] = (f32x4)(0.f);

    ushort* Pw = &Ps[w][0];

    for (int kt = 0; kt < 16; ++kt) {
        // ---- S^T = K * Q^T : A = K-frag (16 keys x 32 d), B^T = Q rows ----
        f32x4 st[4];
#pragma unroll
        for (int mt = 0; mt < 4; ++mt) st[mt] = (f32x4)(0.f);
#pragma unroll
        for (int mt = 0; mt < 4; ++mt) {
            const ushort* kp = kbase + ((size_t)(kt * 64 + mt * 16 + c)) * 512;
            bf16x8 kf0 = *(const bf16x8*)(kp);
            bf16x8 kf1 = *(const bf16x8*)(kp + 32);
            st[mt] = __builtin_amdgcn_mfma_f32_16x16x32_bf16(kf0, qf0, st[mt], 0, 0, 0);
            st[mt] = __builtin_amdgcn_mfma_f32_16x16x32_bf16(kf1, qf1, st[mt], 0, 0, 0);
        }
        // lane holds S^T[key = mt*16 + 4g + r][q = c] -> scaled to log2 domain
        float tv[4][4];
        float tm = -1e30f;
#pragma unroll
        for (int mt = 0; mt < 4; ++mt)
#pragma unroll
            for (int r = 0; r < 4; ++r) {
                tv[mt][r] = st[mt][r] * KSC;
                tm = fmaxf(tm, tv[mt][r]);
            }
        tm = fmaxf(tm, __shfl_xor(tm, 16));
        tm = fmaxf(tm, __shfl_xor(tm, 32));           // per-q tile max, replicated

        float mnew = fmaxf(m, tm);
        float corr = exp2f(m - mnew);
        m = mnew;

        float ps = 0.f;
        ushort pb[4][4];
#pragma unroll
        for (int mt = 0; mt < 4; ++mt)
#pragma unroll
            for (int r = 0; r < 4; ++r) {
                float p = exp2f(tv[mt][r] - m);
                ps += p;
                pb[mt][r] = bfround(p);
            }
        ps += __shfl_xor(ps, 16);
        ps += __shfl_xor(ps, 32);                     // per-q tile sum, replicated
        lsum = lsum * corr + ps;

        // ---- write P (bf16) to wave-private LDS: [q=c][k = mt*16 + 4g + r] ----
        // byte = c*128 + k*2, swizzled ^((c&7)<<4); pack r-pairs -> b32 writes
#pragma unroll
        for (int mt = 0; mt < 4; ++mt)
#pragma unroll
            for (int rp = 0; rp < 2; ++rp) {
                int k = mt * 16 + 4 * g + rp * 2;
                unsigned off = ((unsigned)(c * 128 + k * 2)) ^ ((unsigned)(c & 7) << 4);
                unsigned val = (unsigned)pb[mt][rp * 2] | ((unsigned)pb[mt][rp * 2 + 1] << 16);
                *(unsigned*)((char*)Pw + off) = val;
            }

        // ---- rescale O by corr of its own queries (q = 4g + r) ----
        {
            float c0 = __shfl(corr, 4 * g + 0);
            float c1 = __shfl(corr, 4 * g + 1);
            float c2 = __shfl(corr, 4 * g + 2);
            float c3 = __shfl(corr, 4 * g + 3);
#pragma unroll
            for (int dt = 0; dt < 4; ++dt) {
                o[dt][0] *= c0; o[dt][1] *= c1; o[dt][2] *= c2; o[dt][3] *= c3;
            }
        }

        // ---- O += P * V : A = P-frag (LDS), B^T = V^T rows (global) ----
#pragma unroll
        for (int ks = 0; ks < 2; ++ks) {
            unsigned poff = ((unsigned)(c * 128 + ks * 64 + g * 16)) ^ ((unsigned)(c & 7) << 4);
            bf16x8 pf = *(const bf16x8*)((const char*)Pw + poff);
#pragma unroll
            for (int dt = 0; dt < 4; ++dt) {
                const ushort* vp = vbase + (size_t)(dt * 16 + c) * 1024 + kt * 64 + ks * 32;
                bf16x8 vf = *(const bf16x8*)(vp);
                o[dt] = __builtin_amdgcn_mfma_f32_16x16x32_bf16(pf, vf, o[dt], 0, 0, 0);
            }
        }
    }

    float inv = 1.f / lsum;
    float i0 = __shfl(inv, 4 * g + 0);
    float i1 = __shfl(inv, 4 * g + 1);
    float i2 = __shfl(inv, 4 * g + 2);
    float i3 = __shfl(inv, 4 * g + 3);
    // O layout: row q = 4g + r, col d = dt*16 + c
    float* op = lx + ((size_t)b * 4096 + qbase + 4 * g) * 256 + h * 64 + c;
#pragma unroll
    for (int dt = 0; dt < 4; ++dt) {
        op[dt * 16 + 0 * 256] = o[dt][0] * i0;
        op[dt * 16 + 1 * 256] = o[dt][1] * i1;
        op[dt * 16 + 2 * 256] = o[dt][2] * i2;
        op[dt * 16 + 3 * 256] = o[dt][3] * i3;
    }
}

// ---------------------------------------------------------------------------
// high-frequency windowed attention (2x2 windows), fp32.
// ---------------------------------------------------------------------------
__global__ __launch_bounds__(256) void high_attn_kernel(const float* __restrict__ hqkv,
                                                        float* __restrict__ hx) {
    int idx = blockIdx.x * 256 + threadIdx.x;
    int h = idx & 3;
    int g = (idx >> 2) & 1023;
    int b = idx >> 12;
    int gy = g >> 5, gx = g & 31;
    size_t pbase[4];
    size_t obase[4];
#pragma unroll
    for (int t = 0; t < 4; ++t) {
        int y = gy * 2 + (t >> 1);
        int x = gx * 2 + (t & 1);
        size_t pix = (size_t)(b * 64 + y) * 64 + x;
        pbase[t] = pix * 768;
        obase[t] = pix * 256;
    }
    int co = h * 64;

    float s[4][4];
#pragma unroll
    for (int i = 0; i < 4; ++i)
#pragma unroll
        for (int j = 0; j < 4; ++j) s[i][j] = 0.f;

    for (int dq = 0; dq < 16; ++dq) {
        float4 qv[4], kv[4];
#pragma unroll
        for (int t = 0; t < 4; ++t) {
            qv[t] = *(const float4*)(hqkv + pbase[t] + co + dq * 4);
            kv[t] = *(const float4*)(hqkv + pbase[t] + 256 + co + dq * 4);
        }
#pragma unroll
        for (int i = 0; i < 4; ++i)
#pragma unroll
            for (int j = 0; j < 4; ++j)
                s[i][j] += qv[i].x * kv[j].x + qv[i].y * kv[j].y +
                           qv[i].z * kv[j].z + qv[i].w * kv[j].w;
    }

    float p[4][4];
#pragma unroll
    for (int i = 0; i < 4; ++i) {
        float mx = -1e30f;
#pragma unroll
        for (int j = 0; j < 4; ++j) { s[i][j] *= 0.125f; mx = fmaxf(mx, s[i][j]); }
        float sum = 0.f;
#pragma unroll
        for (int j = 0; j < 4; ++j) { p[i][j] = __expf(s[i][j] - mx); sum += p[i][j]; }
        float inv = 1.f / sum;
#pragma unroll
        for (int j = 0; j < 4; ++j) p[i][j] *= inv;
    }

    for (int dq = 0; dq < 16; ++dq) {
        float4 vv[4];
#pragma unroll
        for (int t = 0; t < 4; ++t)
            vv[t] = *(const float4*)(hqkv + pbase[t] + 512 + co + dq * 4);
#pragma unroll
        for (int i = 0; i < 4; ++i) {
            float4 o;
            o.x = p[i][0] * vv[0].x + p[i][1] * vv[1].x + p[i][2] * vv[2].x + p[i][3] * vv[3].x;
            o.y = p[i][0] * vv[0].y + p[i][1] * vv[1].y + p[i][2] * vv[2].y + p[i][3] * vv[3].y;
            o.z = p[i][0] * vv[0].z + p[i][1] * vv[1].z + p[i][2] * vv[2].z + p[i][3] * vv[3].z;
            o.w = p[i][0] * vv[0].w + p[i][1] * vv[1].w + p[i][2] * vv[2].w + p[i][3] * vv[3].w;
            *(float4*)(hx + obase[i] + co + dq * 4) = o;
        }
    }
}

// ---------------------------------------------------------------------------
extern "C" void kernel_launch(void* const* d_in, const int* in_sizes, int n_in,
                              void* d_out, int out_size, void* d_ws, size_t ws_size,
                              hipStream_t stream) {
    const float* x        = (const float*)d_in[0];
    const float* lq_dw    = (const float*)d_in[1];
    const float* lq_dwb   = (const float*)d_in[2];
    const float* lq_pw    = (const float*)d_in[3];
    const float* lq_pwb   = (const float*)d_in[4];
    const float* lkv_dw   = (const float*)d_in[5];
    const float* lkv_dwb  = (const float*)d_in[6];
    const float* lkv_pw   = (const float*)d_in[7];
    const float* lkv_pwb  = (const float*)d_in[8];
    const float* lproj_dw = (const float*)d_in[9];
    const float* lproj_dwb= (const float*)d_in[10];
    const float* lproj_pw = (const float*)d_in[11];
    const float* lproj_pwb= (const float*)d_in[12];
    const float* hqkv_dw  = (const float*)d_in[13];
    const float* hqkv_dwb = (const float*)d_in[14];
    const float* hqkv_pw  = (const float*)d_in[15];
    const float* hqkv_pwb = (const float*)d_in[16];
    const float* hproj_dw = (const float*)d_in[17];
    const float* hproj_dwb= (const float*)d_in[18];
    const float* hproj_pw = (const float*)d_in[19];
    const float* hproj_pwb= (const float*)d_in[20];
    float* out = (float*)d_out;

    float* ws = (float*)d_ws;
    // workspace layout (float offsets); peak 58,720,256 floats = 235 MB
    ushort* tdwb  = (ushort*)ws;               // [32768,512] bf16 dw scratch (8,388,608 f)
    ushort* wbf   = (ushort*)(ws + 8388608);   // 917,504 bf16 weights (458,752 f)
    float*  high  = ws + 16777216;             // [B,64,64,512]
    float*  low   = ws + 33554432;             // [B,32,32,512]
    float*  l_x   = ws + 37748736;             // [B,4096,256] fp32
    ushort* l_qb  = (ushort*)(ws + 46137344);  // [B,4096,256] bf16
    ushort* l_kvb = (ushort*)(ws + 50331648);  // [B,1024,512] bf16
    ushort* vtb   = (ushort*)(ws + 52428800);  // [b*4+h][64][1024] bf16
    float*  h_qkv = ws + 33554432;             // [B,4096,768] (reuses low..vt after low path)
    float*  h_x   = high;                      // [B,64,64,256] (reuses high)

    // 0. weights -> bf16
    wconv_kernel<<<3584, 256, 0, stream>>>(lq_pw, lkv_pw, lproj_pw, hqkv_pw, hproj_pw, wbf);

    // 1. pool: low + high
    pool_kernel<<<4096, 256, 0, stream>>>(x, low, high);

    // 2. l_q = dsc(x) -> bf16
    dw3x3_bf16_kernel<<<16384, 256, 0, stream>>>(x, lq_dw, lq_dwb, tdwb, BATCH, 64, 64, 512);
    mfma_gemm<512, true><<<dim3(2, 256), 256, 0, stream>>>(tdwb, wbf, lq_pwb,
                                                           l_qb, 256, 0);
    // 3. l_kv = dsc(low) -> bf16, then V^T
    dw3x3_bf16_kernel<<<4096, 256, 0, stream>>>(low, lkv_dw, lkv_dwb, tdwb, BATCH, 32, 32, 512);
    mfma_gemm<512, true><<<dim3(4, 64), 256, 0, stream>>>(tdwb, wbf + 131072, lkv_pwb,
                                                          l_kvb, 512, 0);
    vtrans_kernel<<<128, 256, 0, stream>>>(l_kvb, vtb);

    // 4. low attention (MFMA flash)
    low_attn_mfma<<<2048, 256, 0, stream>>>(l_qb, l_kvb, vtb, l_x);

    // 5. l_out = dsc(l_x) -> out cols 0..255
    dw3x3_bf16_kernel<<<8192, 256, 0, stream>>>(l_x, lproj_dw, lproj_dwb, tdwb, BATCH, 64, 64, 256);
    mfma_gemm<256, false><<<dim3(2, 256), 256, 0, stream>>>(tdwb, wbf + 393216, lproj_pwb,
                                                            out, 512, 0);
    // 6. h_qkv = dsc(high)
    dw3x3_bf16_kernel<<<16384, 256, 0, stream>>>(high, hqkv_dw, hqkv_dwb, tdwb, BATCH, 64, 64, 512);
    mfma_gemm<512, false><<<dim3(6, 256), 256, 0, stream>>>(tdwb, wbf + 458752, hqkv_pwb,
                                                            h_qkv, 768, 0);
    // 7. high (windowed) attention
    high_attn_kernel<<<128, 256, 0, stream>>>(h_qkv, h_x);

    // 8. h_out = dsc(h_x) -> out cols 256..511
    dw3x3_bf16_kernel<<<8192, 256, 0, stream>>>(h_x, hproj_dw, hproj_dwb, tdwb, BATCH, 64, 64, 256);
    mfma_gemm<256, false><<<dim3(2, 256), 256, 0, stream>>>(tdwb, wbf + 851968, hproj_pwb,
                                                            out, 512, 256);
}